// Round 11
// baseline (205.136 us; speedup 1.0000x reference)
//
#include <hip/hip_runtime.h>

// MACE symmetric contraction, B=4096 nodes, C=256 channels, I=16.
//
// Per (b,c):  s[b,c] = sum_p x_p * t[b,p],
//   t[b,p] = sum_{k<256} U3w[c,p,q,i]*x_q*x_i   (k=q*16+i)
//          + sum_q c2[c,p,q]*x_q (k=256+q)  +  c1[c,p] (k=272)
// => K=273 (pad 288=9*32) matmul on mfma_f32_16x16x32_bf16.
// A = coeff[p,k] (regs, static per wave), B = y[k,node] built per tile.
//
// R11: latency attack on the MFMA dependency chain. R10 (zero-alloca, ~35us)
// is bound by a 9-deep serially-dependent MFMA chain per tile at ~3
// waves/SIMD. Now: 2 accumulators per tile (even/odd steps, fp32 add at end)
// x 2 tiles interleaved = 4 independent chains; >=3 MFMAs between dependent
// uses. All values in named by-value scalars through __forceinline__ fns —
// ZERO allocas (R8/R9: PromoteAlloca stripes private arrays into LDS when no
// __shared__ is declared -> 3.1e7 bank-conflict cycles; never do that again).
// Harness floor: ws-poison fill 40us + d_in restore ~25us + misc => ~110us
// of dur_us is uncontrollable (fills run at 6.6 TB/s, the write ceiling).

#define B_NODES 4096
#define C_CH    256
#define K3      23
#define K2      4

#define KSTEPS   9
#define KB_ELEMS (KSTEPS * 64 * 8)   // 4608 bf16 per channel
#define KB_U32   (KB_ELEMS / 2)      // 2304 u32 per channel

#define TILES_PER_WAVE 8             // 128 nodes per wave

typedef short    short8 __attribute__((ext_vector_type(8)));
typedef float    f32x4  __attribute__((ext_vector_type(4)));
typedef unsigned u32x4  __attribute__((ext_vector_type(4)));

// ws layout (bytes): [bfrag: C*4608*2][sT: C*B*4]
static constexpr size_t OFF_BF_BYTES = 0;
static constexpr size_t OFF_ST_BYTES = (size_t)C_CH * KB_ELEMS * 2;

__device__ inline unsigned short f2bf_rne(float f) {
  unsigned u = __builtin_bit_cast(unsigned, f);
  unsigned r = u + 0x7FFFu + ((u >> 16) & 1u);
  return (unsigned short)(r >> 16);
}

#define F2U(f) __builtin_bit_cast(unsigned, (f))
// pack two f32 (truncate-to-bf16 high halves) into one u32: [hi16(YH)|hi16(YL)]
#define PK2(YH, YL) __builtin_amdgcn_perm(F2U(YH), F2U(YL), 0x07060302u)

// ---------------------------------------------------------------------------
// Kernel 1: coeff in fragment order (lane&15 = p, k = s*32+(lane>>4)*8+j).
// grid (9 steps, 32 channel-groups of 8); steps 0..7 stage a 47 KB U3 slice.
// ---------------------------------------------------------------------------
__global__ __launch_bounds__(256) void precompute_bfrag(
    const float* __restrict__ U3, const float* __restrict__ U2,
    const float* __restrict__ U1, const float* __restrict__ w3,
    const float* __restrict__ w2, const float* __restrict__ w1,
    unsigned int* __restrict__ bfrag_u32) {
  const int s  = blockIdx.x;        // K-step 0..8
  const int c0 = blockIdx.y * 8;    // 8 channels per block
  const int t  = threadIdx.x;
  const int lane = t >> 2;          // fragment lane
  const int jj   = (t & 3) * 2;     // 0,2,4,6
  const int p = lane & 15, g = lane >> 4;

  __shared__ float su3[512 * 23];   // rows: p*32 + qb*16 + i

  if (s < 8) {
    for (int l = t; l < 512 * 23; l += 256) {
      const int row = l / 23, col = l - row * 23;
      const int pp = row >> 5, qb = (row >> 4) & 1, ii = row & 15;
      su3[l] = U3[(size_t)((pp * 16 + (2 * s + qb)) * 16 + ii) * K3 + col];
    }
    __syncthreads();

    const int r0 = p * 32 + (g >> 1) * 16 + (g & 1) * 8 + jj;
    float u0[K3], u1[K3];
#pragma unroll
    for (int k3 = 0; k3 < K3; ++k3) {
      u0[k3] = su3[(size_t)r0 * K3 + k3];
      u1[k3] = su3[(size_t)(r0 + 1) * K3 + k3];
    }
#pragma unroll
    for (int ch = 0; ch < 8; ++ch) {
      const int c = c0 + ch;
      float a0 = 0.f, a1 = 0.f;
#pragma unroll
      for (int k3 = 0; k3 < K3; ++k3) {
        const float wv = w3[c * K3 + k3];   // uniform -> scalar load
        a0 += u0[k3] * wv;
        a1 += u1[k3] * wv;
      }
      bfrag_u32[(size_t)c * KB_U32 + s * 256 + t] =
          (unsigned)f2bf_rne(a0) | ((unsigned)f2bf_rne(a1) << 16);
    }
  } else {
    // s == 8: linear rows (x_q), constant row (k==272), pad 0.
#pragma unroll
    for (int ch = 0; ch < 8; ++ch) {
      const int c = c0 + ch;
      float v0 = 0.f, v1 = 0.f;
#pragma unroll
      for (int e = 0; e < 2; ++e) {
        const int k = 256 + g * 8 + jj + e;
        float a = 0.f;
        if (k < 272) {
          const int q = k - 256;
#pragma unroll
          for (int k2 = 0; k2 < K2; ++k2)
            a += U2[(size_t)(p * 16 + q) * K2 + k2] * w2[c * K2 + k2];
        } else if (k == 272) {
          a = U1[p] * w1[c];
        }
        if (e == 0) v0 = a; else v1 = a;
      }
      bfrag_u32[(size_t)c * KB_U32 + s * 256 + t] =
          (unsigned)f2bf_rne(v0) | ((unsigned)f2bf_rne(v1) << 16);
    }
  }
}

// ---------------------------------------------------------------------------
// Kernel 2 helpers: all by-value scalar/vector params -> no allocas ever.
// ---------------------------------------------------------------------------
__device__ __forceinline__ f32x4 qstep(short8 bfv, float xq,
                                       float h0, float h1, float h2, float h3,
                                       float h4, float h5, float h6, float h7,
                                       f32x4 acc) {
  u32x4 u;
  u[0] = PK2(xq * h1, xq * h0);
  u[1] = PK2(xq * h3, xq * h2);
  u[2] = PK2(xq * h5, xq * h4);
  u[3] = PK2(xq * h7, xq * h6);
  return __builtin_amdgcn_mfma_f32_16x16x32_bf16(
      bfv, __builtin_bit_cast(short8, u), acc, 0, 0, 0);
}

__device__ __forceinline__ f32x4 lstep(short8 bfv, bool glin, float cst,
                                       float h0, float h1, float h2, float h3,
                                       float h4, float h5, float h6, float h7,
                                       f32x4 acc) {
  const float y0 = glin ? h0 : cst;
  const float y1 = glin ? h1 : 0.f;
  const float y2 = glin ? h2 : 0.f;
  const float y3 = glin ? h3 : 0.f;
  const float y4 = glin ? h4 : 0.f;
  const float y5 = glin ? h5 : 0.f;
  const float y6 = glin ? h6 : 0.f;
  const float y7 = glin ? h7 : 0.f;
  u32x4 u;
  u[0] = PK2(y1, y0);
  u[1] = PK2(y3, y2);
  u[2] = PK2(y5, y4);
  u[3] = PK2(y7, y6);
  return __builtin_amdgcn_mfma_f32_16x16x32_bf16(
      bfv, __builtin_bit_cast(short8, u), acc, 0, 0, 0);
}

// Compute TWO tiles with 2 accumulators each (4 independent MFMA chains,
// explicitly interleaved) and store both results.
__device__ __forceinline__ void pair_body(
    short8 bf0, short8 bf1, short8 bf2, short8 bf3, short8 bf4,
    short8 bf5, short8 bf6, short8 bf7, short8 bf8,
    float4 a0, float4 a1, float4 a2, float4 a3,
    float4 b0, float4 b1, float4 b2, float4 b3,
    bool ghi, bool gq, bool glin, float cst, int g, int n,
    float* sTrow, int Ta, int Tb) {
  // i-half selects (xh) and q selects (xq) for both tiles.
  const float hA0 = ghi ? a2.x : a0.x, hA1 = ghi ? a2.y : a0.y;
  const float hA2 = ghi ? a2.z : a0.z, hA3 = ghi ? a2.w : a0.w;
  const float hA4 = ghi ? a3.x : a1.x, hA5 = ghi ? a3.y : a1.y;
  const float hA6 = ghi ? a3.z : a1.z, hA7 = ghi ? a3.w : a1.w;
  const float hB0 = ghi ? b2.x : b0.x, hB1 = ghi ? b2.y : b0.y;
  const float hB2 = ghi ? b2.z : b0.z, hB3 = ghi ? b2.w : b0.w;
  const float hB4 = ghi ? b3.x : b1.x, hB5 = ghi ? b3.y : b1.y;
  const float hB6 = ghi ? b3.z : b1.z, hB7 = ghi ? b3.w : b1.w;
  const float qA0 = gq ? a0.y : a0.x, qA1 = gq ? a0.w : a0.z;
  const float qA2 = gq ? a1.y : a1.x, qA3 = gq ? a1.w : a1.z;
  const float qA4 = gq ? a2.y : a2.x, qA5 = gq ? a2.w : a2.z;
  const float qA6 = gq ? a3.y : a3.x, qA7 = gq ? a3.w : a3.z;
  const float qB0 = gq ? b0.y : b0.x, qB1 = gq ? b0.w : b0.z;
  const float qB2 = gq ? b1.y : b1.x, qB3 = gq ? b1.w : b1.z;
  const float qB4 = gq ? b2.y : b2.x, qB5 = gq ? b2.w : b2.z;
  const float qB6 = gq ? b3.y : b3.x, qB7 = gq ? b3.w : b3.z;

  f32x4 aA0 = (f32x4){0.f, 0.f, 0.f, 0.f};
  f32x4 aA1 = (f32x4){0.f, 0.f, 0.f, 0.f};
  f32x4 aB0 = (f32x4){0.f, 0.f, 0.f, 0.f};
  f32x4 aB1 = (f32x4){0.f, 0.f, 0.f, 0.f};

  // 4 chains, round-robin: dependent reuse is >=3 MFMAs away.
  aA0 = qstep(bf0, qA0, hA0, hA1, hA2, hA3, hA4, hA5, hA6, hA7, aA0);
  aB0 = qstep(bf0, qB0, hB0, hB1, hB2, hB3, hB4, hB5, hB6, hB7, aB0);
  aA1 = qstep(bf1, qA1, hA0, hA1, hA2, hA3, hA4, hA5, hA6, hA7, aA1);
  aB1 = qstep(bf1, qB1, hB0, hB1, hB2, hB3, hB4, hB5, hB6, hB7, aB1);
  aA0 = qstep(bf2, qA2, hA0, hA1, hA2, hA3, hA4, hA5, hA6, hA7, aA0);
  aB0 = qstep(bf2, qB2, hB0, hB1, hB2, hB3, hB4, hB5, hB6, hB7, aB0);
  aA1 = qstep(bf3, qA3, hA0, hA1, hA2, hA3, hA4, hA5, hA6, hA7, aA1);
  aB1 = qstep(bf3, qB3, hB0, hB1, hB2, hB3, hB4, hB5, hB6, hB7, aB1);
  aA0 = qstep(bf4, qA4, hA0, hA1, hA2, hA3, hA4, hA5, hA6, hA7, aA0);
  aB0 = qstep(bf4, qB4, hB0, hB1, hB2, hB3, hB4, hB5, hB6, hB7, aB0);
  aA1 = qstep(bf5, qA5, hA0, hA1, hA2, hA3, hA4, hA5, hA6, hA7, aA1);
  aB1 = qstep(bf5, qB5, hB0, hB1, hB2, hB3, hB4, hB5, hB6, hB7, aB1);
  aA0 = qstep(bf6, qA6, hA0, hA1, hA2, hA3, hA4, hA5, hA6, hA7, aA0);
  aB0 = qstep(bf6, qB6, hB0, hB1, hB2, hB3, hB4, hB5, hB6, hB7, aB0);
  aA1 = qstep(bf7, qA7, hA0, hA1, hA2, hA3, hA4, hA5, hA6, hA7, aA1);
  aB1 = qstep(bf7, qB7, hB0, hB1, hB2, hB3, hB4, hB5, hB6, hB7, aB1);
  aA0 = lstep(bf8, glin, cst, hA0, hA1, hA2, hA3, hA4, hA5, hA6, hA7, aA0);
  aB0 = lstep(bf8, glin, cst, hB0, hB1, hB2, hB3, hB4, hB5, hB6, hB7, aB0);

  const f32x4 accA = aA0 + aA1;
  const f32x4 accB = aB0 + aB1;

  // Epilogue. D[row p = g*4+r][col node = n]; lane's x4 IS its node's row.
  const float4 xsA = (g & 2) ? ((g & 1) ? a3 : a2) : ((g & 1) ? a1 : a0);
  const float4 xsB = (g & 2) ? ((g & 1) ? b3 : b2) : ((g & 1) ? b1 : b0);
  float vA = accA[0] * xsA.x + accA[1] * xsA.y + accA[2] * xsA.z + accA[3] * xsA.w;
  float vB = accB[0] * xsB.x + accB[1] * xsB.y + accB[2] * xsB.z + accB[3] * xsB.w;
  vA += __shfl_xor(vA, 16);
  vB += __shfl_xor(vB, 16);
  vA += __shfl_xor(vA, 32);
  vB += __shfl_xor(vB, 32);
  if (g == 0) {
    sTrow[Ta * 16 + n] = vA;
    sTrow[Tb * 16 + n] = vB;
  }
}

// ---------------------------------------------------------------------------
// Kernel 2: wave-autonomous MFMA contraction, zero allocas, 4 MFMA chains.
// Block = 256 thr (4 waves); wave w owns channel cg0+w; 128 nodes/wave.
// ---------------------------------------------------------------------------
__global__ __launch_bounds__(256)
__attribute__((amdgpu_waves_per_eu(2, 4)))
void contract_mfma(
    const float* __restrict__ x, const short8* __restrict__ bfragv,
    float* __restrict__ sT) {
  const int cg0 = blockIdx.x * 4;                    // channel group (fastest)
  const int nb0 = blockIdx.y * (TILES_PER_WAVE * 16);
  const int t   = threadIdx.x;
  const int w = t >> 6, lane = t & 63, n = lane & 15, g = lane >> 4;
  const int ch = cg0 + w;

  // Coeff fragments: 9 coalesced dwordx4 into NAMED registers (36 VGPRs).
  const short8* bp = bfragv + (size_t)ch * (KSTEPS * 64);
  const short8 bf0 = bp[0 * 64 + lane];
  const short8 bf1 = bp[1 * 64 + lane];
  const short8 bf2 = bp[2 * 64 + lane];
  const short8 bf3 = bp[3 * 64 + lane];
  const short8 bf4 = bp[4 * 64 + lane];
  const short8 bf5 = bp[5 * 64 + lane];
  const short8 bf6 = bp[6 * 64 + lane];
  const short8 bf7 = bp[7 * 64 + lane];
  const short8 bf8 = bp[8 * 64 + lane];

  const bool  ghi  = (g & 1) != 0;        // i-half: i = (g&1)*8 + j
  const bool  gq   = ((g >> 1) & 1) != 0; // q = 2s + (g>>1)
  const bool  glin = (g < 2);             // step-8 linear rows live in g<2
  const float cst  = (g == 2) ? 1.0f : 0.0f;  // step-8 constant row
  float* sTrow = sT + (size_t)ch * B_NODES + nb0;

  // x address for lane's node in tile T: row (nb0+T*16+n), this wave's 64B.
  const float* xb = x + (size_t)(nb0 + n) * (C_CH * 16) + (size_t)ch * 16;
  const size_t tstride = (size_t)16 * C_CH * 16;     // 16 nodes

  // Named register double-buffer at PAIR granularity. No arrays ever.
  float4 ra0, ra1, ra2, ra3, rb0, rb1, rb2, rb3;   // live pair
  float4 rc0, rc1, rc2, rc3, rd0, rd1, rd2, rd3;   // prefetch pair
  {
    const float4* p = (const float4*)xb;
    ra0 = p[0]; ra1 = p[1]; ra2 = p[2]; ra3 = p[3];
    const float4* q = (const float4*)(xb + tstride);
    rb0 = q[0]; rb1 = q[1]; rb2 = q[2]; rb3 = q[3];
  }
  // Stage 0: prefetch tiles 2,3; compute tiles 0,1.
  {
    const float4* p = (const float4*)(xb + 2 * tstride);
    rc0 = p[0]; rc1 = p[1]; rc2 = p[2]; rc3 = p[3];
    const float4* q = (const float4*)(xb + 3 * tstride);
    rd0 = q[0]; rd1 = q[1]; rd2 = q[2]; rd3 = q[3];
  }
  pair_body(bf0, bf1, bf2, bf3, bf4, bf5, bf6, bf7, bf8,
            ra0, ra1, ra2, ra3, rb0, rb1, rb2, rb3,
            ghi, gq, glin, cst, g, n, sTrow, 0, 1);
  // Stage 1: prefetch tiles 4,5; compute tiles 2,3.
  {
    const float4* p = (const float4*)(xb + 4 * tstride);
    ra0 = p[0]; ra1 = p[1]; ra2 = p[2]; ra3 = p[3];
    const float4* q = (const float4*)(xb + 5 * tstride);
    rb0 = q[0]; rb1 = q[1]; rb2 = q[2]; rb3 = q[3];
  }
  pair_body(bf0, bf1, bf2, bf3, bf4, bf5, bf6, bf7, bf8,
            rc0, rc1, rc2, rc3, rd0, rd1, rd2, rd3,
            ghi, gq, glin, cst, g, n, sTrow, 2, 3);
  // Stage 2: prefetch tiles 6,7; compute tiles 4,5.
  {
    const float4* p = (const float4*)(xb + 6 * tstride);
    rc0 = p[0]; rc1 = p[1]; rc2 = p[2]; rc3 = p[3];
    const float4* q = (const float4*)(xb + 7 * tstride);
    rd0 = q[0]; rd1 = q[1]; rd2 = q[2]; rd3 = q[3];
  }
  pair_body(bf0, bf1, bf2, bf3, bf4, bf5, bf6, bf7, bf8,
            ra0, ra1, ra2, ra3, rb0, rb1, rb2, rb3,
            ghi, gq, glin, cst, g, n, sTrow, 4, 5);
  // Stage 3: compute tiles 6,7.
  pair_body(bf0, bf1, bf2, bf3, bf4, bf5, bf6, bf7, bf8,
            rc0, rc1, rc2, rc3, rd0, rd1, rd2, rd3,
            ghi, gq, glin, cst, g, n, sTrow, 6, 7);
}

// ---------------------------------------------------------------------------
// Kernel 3: out[b,d] = (1/16) * sum_c sT[c,b] * W[c,d]  (fp32, 64x64 tiles)
// ---------------------------------------------------------------------------
__global__ __launch_bounds__(256) void linear_kernel(
    const float* __restrict__ sT, const float* __restrict__ W,
    float* __restrict__ out) {
  const int b0 = blockIdx.x * 64;
  const int d0 = blockIdx.y * 64;
  const int t  = threadIdx.x;
  const int tx = t & 15;
  const int ty = t >> 4;

  __shared__ float As[16][64];
  __shared__ float Bs[16][64];
  float acc[4][4] = {};

  for (int k0 = 0; k0 < C_CH; k0 += 16) {
    const int kk  = t >> 6;
    const int col = t & 63;
#pragma unroll
    for (int r = 0; r < 4; ++r) {
      As[kk + r * 4][col] = sT[(size_t)(k0 + kk + r * 4) * B_NODES + b0 + col];
      Bs[kk + r * 4][col] = W[(size_t)(k0 + kk + r * 4) * C_CH + d0 + col];
    }
    __syncthreads();
#pragma unroll
    for (int k = 0; k < 16; ++k) {
      float a[4], bv[4];
#pragma unroll
      for (int i = 0; i < 4; ++i) a[i] = As[k][ty * 4 + i];
#pragma unroll
      for (int j = 0; j < 4; ++j) bv[j] = Bs[k][tx * 4 + j];
#pragma unroll
      for (int i = 0; i < 4; ++i)
#pragma unroll
        for (int j = 0; j < 4; ++j) acc[i][j] += a[i] * bv[j];
    }
    __syncthreads();
  }

#pragma unroll
  for (int i = 0; i < 4; ++i) {
    float4 v = make_float4(acc[i][0] * 0.0625f, acc[i][1] * 0.0625f,
                           acc[i][2] * 0.0625f, acc[i][3] * 0.0625f);
    *(float4*)(out + (size_t)(b0 + ty * 4 + i) * C_CH + d0 + tx * 4) = v;
  }
}

extern "C" void kernel_launch(void* const* d_in, const int* in_sizes, int n_in,
                              void* d_out, int out_size, void* d_ws, size_t ws_size,
                              hipStream_t stream) {
  const float* x  = (const float*)d_in[0];
  const float* U3 = (const float*)d_in[1];
  const float* U2 = (const float*)d_in[2];
  const float* U1 = (const float*)d_in[3];
  const float* w3 = (const float*)d_in[4];
  const float* w2 = (const float*)d_in[5];
  const float* w1 = (const float*)d_in[6];
  const float* Wl = (const float*)d_in[7];

  unsigned int* bfrag = (unsigned int*)((char*)d_ws + OFF_BF_BYTES);
  float*        sT    = (float*)((char*)d_ws + OFF_ST_BYTES);
  float*        out   = (float*)d_out;

  precompute_bfrag<<<dim3(KSTEPS, C_CH / 8), dim3(256), 0, stream>>>(
      U3, U2, U1, w3, w2, w1, bfrag);
  contract_mfma<<<dim3(C_CH / 4, B_NODES / (TILES_PER_WAVE * 16)), dim3(256), 0, stream>>>(
      x, (const short8*)bfrag, sT);
  linear_kernel<<<dim3(B_NODES / 64, C_CH / 64), dim3(256), 0, stream>>>(sT, Wl, out);
}

// Round 12
// 152.569 us; speedup vs baseline: 1.3445x; 1.3445x over previous
//
#include <hip/hip_runtime.h>

// MACE symmetric contraction, B=4096 nodes, C=256 channels, I=16.
//
// Per (b,c):  s[b,c] = sum_p x_p * t[b,p],
//   t[b,p] = sum_{k<256} U3w[c,p,q,i]*x_q*x_i   (k=q*16+i)
//          + sum_q c2[c,p,q]*x_q (k=256+q)  +  c1[c,p] (k=272)
// => K=273 (pad 288=9*32) matmul on mfma_f32_16x16x32_bf16.
// A = coeff[p,k] (regs, static per wave), B = y[k,node] built per tile.
//
// R12 = R10 (best known) + dual accumulators per tile (even/odd K-steps,
// +4 VGPRs only). R11's 4-chain/pair-prefetch variant spilled (~150 live
// regs -> 153 MB scratch WRITE, contract 35->89us): the allocator chases
// occupancy and spills anything over ~110 live regs, so ILP must come cheap.
// Zero allocas everywhere (R8/R9: PromoteAlloca stripes private arrays into
// LDS when no __shared__ is declared -> 3.1e7 bank-conflict cycles).
// Harness floor: ws-poison fill 40us @6.6TB/s + d_in restore ~25us + misc
// => ~110us of dur_us is uncontrollable.

#define B_NODES 4096
#define C_CH    256
#define K3      23
#define K2      4

#define KSTEPS   9
#define KB_ELEMS (KSTEPS * 64 * 8)   // 4608 bf16 per channel
#define KB_U32   (KB_ELEMS / 2)      // 2304 u32 per channel

#define TILES_PER_WAVE 8             // 128 nodes per wave

typedef short    short8 __attribute__((ext_vector_type(8)));
typedef float    f32x4  __attribute__((ext_vector_type(4)));
typedef unsigned u32x4  __attribute__((ext_vector_type(4)));

// ws layout (bytes): [bfrag: C*4608*2][sT: C*B*4]
static constexpr size_t OFF_BF_BYTES = 0;
static constexpr size_t OFF_ST_BYTES = (size_t)C_CH * KB_ELEMS * 2;

__device__ inline unsigned short f2bf_rne(float f) {
  unsigned u = __builtin_bit_cast(unsigned, f);
  unsigned r = u + 0x7FFFu + ((u >> 16) & 1u);
  return (unsigned short)(r >> 16);
}

#define F2U(f) __builtin_bit_cast(unsigned, (f))
// pack two f32 (truncate-to-bf16 high halves) into one u32: [hi16(YH)|hi16(YL)]
#define PK2(YH, YL) __builtin_amdgcn_perm(F2U(YH), F2U(YL), 0x07060302u)

// ---------------------------------------------------------------------------
// Kernel 1: coeff in fragment order (lane&15 = p, k = s*32+(lane>>4)*8+j).
// grid (9 steps, 32 channel-groups of 8); steps 0..7 stage a 47 KB U3 slice.
// ---------------------------------------------------------------------------
__global__ __launch_bounds__(256) void precompute_bfrag(
    const float* __restrict__ U3, const float* __restrict__ U2,
    const float* __restrict__ U1, const float* __restrict__ w3,
    const float* __restrict__ w2, const float* __restrict__ w1,
    unsigned int* __restrict__ bfrag_u32) {
  const int s  = blockIdx.x;        // K-step 0..8
  const int c0 = blockIdx.y * 8;    // 8 channels per block
  const int t  = threadIdx.x;
  const int lane = t >> 2;          // fragment lane
  const int jj   = (t & 3) * 2;     // 0,2,4,6
  const int p = lane & 15, g = lane >> 4;

  __shared__ float su3[512 * 23];   // rows: p*32 + qb*16 + i

  if (s < 8) {
    for (int l = t; l < 512 * 23; l += 256) {
      const int row = l / 23, col = l - row * 23;
      const int pp = row >> 5, qb = (row >> 4) & 1, ii = row & 15;
      su3[l] = U3[(size_t)((pp * 16 + (2 * s + qb)) * 16 + ii) * K3 + col];
    }
    __syncthreads();

    const int r0 = p * 32 + (g >> 1) * 16 + (g & 1) * 8 + jj;
    float u0[K3], u1[K3];
#pragma unroll
    for (int k3 = 0; k3 < K3; ++k3) {
      u0[k3] = su3[(size_t)r0 * K3 + k3];
      u1[k3] = su3[(size_t)(r0 + 1) * K3 + k3];
    }
#pragma unroll
    for (int ch = 0; ch < 8; ++ch) {
      const int c = c0 + ch;
      float a0 = 0.f, a1 = 0.f;
#pragma unroll
      for (int k3 = 0; k3 < K3; ++k3) {
        const float wv = w3[c * K3 + k3];   // uniform -> scalar load
        a0 += u0[k3] * wv;
        a1 += u1[k3] * wv;
      }
      bfrag_u32[(size_t)c * KB_U32 + s * 256 + t] =
          (unsigned)f2bf_rne(a0) | ((unsigned)f2bf_rne(a1) << 16);
    }
  } else {
    // s == 8: linear rows (x_q), constant row (k==272), pad 0.
#pragma unroll
    for (int ch = 0; ch < 8; ++ch) {
      const int c = c0 + ch;
      float v0 = 0.f, v1 = 0.f;
#pragma unroll
      for (int e = 0; e < 2; ++e) {
        const int k = 256 + g * 8 + jj + e;
        float a = 0.f;
        if (k < 272) {
          const int q = k - 256;
#pragma unroll
          for (int k2 = 0; k2 < K2; ++k2)
            a += U2[(size_t)(p * 16 + q) * K2 + k2] * w2[c * K2 + k2];
        } else if (k == 272) {
          a = U1[p] * w1[c];
        }
        if (e == 0) v0 = a; else v1 = a;
      }
      bfrag_u32[(size_t)c * KB_U32 + s * 256 + t] =
          (unsigned)f2bf_rne(v0) | ((unsigned)f2bf_rne(v1) << 16);
    }
  }
}

// ---------------------------------------------------------------------------
// Kernel 2: wave-autonomous MFMA contraction, zero allocas.
// Block = 256 thr (4 waves); wave w owns channel c0+w; 128 nodes/wave.
// Dual accumulators per tile: even steps -> acc, odd -> acc2 (chain 9 -> 5).
// ---------------------------------------------------------------------------

// One quadratic K-step: af rows = xq * xh[0..7], packed bf16.
#define QSTEP(BF, XQ, ACC)                                                     \
  __builtin_amdgcn_mfma_f32_16x16x32_bf16((BF),                                \
      __builtin_bit_cast(short8, (u32x4){                                      \
          PK2((XQ) * xh1, (XQ) * xh0), PK2((XQ) * xh3, (XQ) * xh2),            \
          PK2((XQ) * xh5, (XQ) * xh4), PK2((XQ) * xh7, (XQ) * xh6)}),          \
      (ACC), 0, 0, 0)

#define TILE_BODY(X0, X1, X2, X3, Tc)                                          \
  do {                                                                         \
    const float xh0 = ghi ? (X2).x : (X0).x;                                   \
    const float xh1 = ghi ? (X2).y : (X0).y;                                   \
    const float xh2 = ghi ? (X2).z : (X0).z;                                   \
    const float xh3 = ghi ? (X2).w : (X0).w;                                   \
    const float xh4 = ghi ? (X3).x : (X1).x;                                   \
    const float xh5 = ghi ? (X3).y : (X1).y;                                   \
    const float xh6 = ghi ? (X3).z : (X1).z;                                   \
    const float xh7 = ghi ? (X3).w : (X1).w;                                   \
    const float xq0 = gq ? (X0).y : (X0).x;                                    \
    const float xq1 = gq ? (X0).w : (X0).z;                                    \
    const float xq2 = gq ? (X1).y : (X1).x;                                    \
    const float xq3 = gq ? (X1).w : (X1).z;                                    \
    const float xq4 = gq ? (X2).y : (X2).x;                                    \
    const float xq5 = gq ? (X2).w : (X2).z;                                    \
    const float xq6 = gq ? (X3).y : (X3).x;                                    \
    const float xq7 = gq ? (X3).w : (X3).z;                                    \
    f32x4 acc  = (f32x4){0.f, 0.f, 0.f, 0.f};                                  \
    f32x4 acc2 = (f32x4){0.f, 0.f, 0.f, 0.f};                                  \
    acc  = QSTEP(bf0, xq0, acc);                                               \
    acc2 = QSTEP(bf1, xq1, acc2);                                              \
    acc  = QSTEP(bf2, xq2, acc);                                               \
    acc2 = QSTEP(bf3, xq3, acc2);                                              \
    acc  = QSTEP(bf4, xq4, acc);                                               \
    acc2 = QSTEP(bf5, xq5, acc2);                                              \
    acc  = QSTEP(bf6, xq6, acc);                                               \
    acc2 = QSTEP(bf7, xq7, acc2);                                              \
    {                                                                          \
      const float y0 = glin ? xh0 : cst;                                       \
      const float y1 = glin ? xh1 : 0.f;                                       \
      const float y2 = glin ? xh2 : 0.f;                                       \
      const float y3 = glin ? xh3 : 0.f;                                       \
      const float y4 = glin ? xh4 : 0.f;                                       \
      const float y5 = glin ? xh5 : 0.f;                                       \
      const float y6 = glin ? xh6 : 0.f;                                       \
      const float y7 = glin ? xh7 : 0.f;                                       \
      acc = __builtin_amdgcn_mfma_f32_16x16x32_bf16(bf8,                       \
          __builtin_bit_cast(short8, (u32x4){PK2(y1, y0), PK2(y3, y2),         \
                                             PK2(y5, y4), PK2(y7, y6)}),       \
          acc, 0, 0, 0);                                                       \
    }                                                                          \
    acc = acc + acc2;                                                          \
    const float4 xs = (g & 2) ? ((g & 1) ? (X3) : (X2))                        \
                              : ((g & 1) ? (X1) : (X0));                       \
    float v = acc[0] * xs.x + acc[1] * xs.y + acc[2] * xs.z + acc[3] * xs.w;   \
    v += __shfl_xor(v, 16);                                                    \
    v += __shfl_xor(v, 32);                                                    \
    if (g == 0) sTrow[(Tc) * 16 + n] = v;                                      \
  } while (0)

__global__ __launch_bounds__(256)
__attribute__((amdgpu_waves_per_eu(2, 4)))
void contract_mfma(
    const float* __restrict__ x, const short8* __restrict__ bfragv,
    float* __restrict__ sT) {
  const int c0  = blockIdx.x * 4;                    // channel group (fastest)
  const int nb0 = blockIdx.y * (TILES_PER_WAVE * 16);
  const int t   = threadIdx.x;
  const int w = t >> 6, lane = t & 63, n = lane & 15, g = lane >> 4;
  const int ch = c0 + w;

  // Coeff fragments: 9 coalesced dwordx4 into NAMED registers (36 VGPRs).
  const short8* bp = bfragv + (size_t)ch * (KSTEPS * 64);
  const short8 bf0 = bp[0 * 64 + lane];
  const short8 bf1 = bp[1 * 64 + lane];
  const short8 bf2 = bp[2 * 64 + lane];
  const short8 bf3 = bp[3 * 64 + lane];
  const short8 bf4 = bp[4 * 64 + lane];
  const short8 bf5 = bp[5 * 64 + lane];
  const short8 bf6 = bp[6 * 64 + lane];
  const short8 bf7 = bp[7 * 64 + lane];
  const short8 bf8 = bp[8 * 64 + lane];

  const bool  ghi  = (g & 1) != 0;        // i-half: i = (g&1)*8 + j
  const bool  gq   = ((g >> 1) & 1) != 0; // q = 2s + (g>>1)
  const bool  glin = (g < 2);             // step-8 linear rows live in g<2
  const float cst  = (g == 2) ? 1.0f : 0.0f;  // step-8 constant row
  float* sTrow = sT + (size_t)ch * B_NODES + nb0;

  // x address for lane's node in tile T: row (nb0+T*16+n), this wave's 64B.
  const float* xb = x + (size_t)(nb0 + n) * (C_CH * 16) + (size_t)ch * 16;
  const size_t tstride = (size_t)16 * C_CH * 16;     // 16 nodes

  // Named register double-buffer. No arrays, no address-of.
  float4 a0, a1, a2, a3, b0, b1, b2, b3;
  {
    const float4* p = (const float4*)xb;
    a0 = p[0]; a1 = p[1]; a2 = p[2]; a3 = p[3];
  }

#pragma unroll
  for (int TT = 0; TT < TILES_PER_WAVE / 2; ++TT) {
    {
      const float4* p = (const float4*)(xb + (size_t)(2 * TT + 1) * tstride);
      b0 = p[0]; b1 = p[1]; b2 = p[2]; b3 = p[3];
    }
    TILE_BODY(a0, a1, a2, a3, 2 * TT);
    if (TT + 1 < TILES_PER_WAVE / 2) {
      const float4* p = (const float4*)(xb + (size_t)(2 * TT + 2) * tstride);
      a0 = p[0]; a1 = p[1]; a2 = p[2]; a3 = p[3];
    }
    TILE_BODY(b0, b1, b2, b3, 2 * TT + 1);
  }
}

// ---------------------------------------------------------------------------
// Kernel 3: out[b,d] = (1/16) * sum_c sT[c,b] * W[c,d]  (fp32, 64x64 tiles)
// ---------------------------------------------------------------------------
__global__ __launch_bounds__(256) void linear_kernel(
    const float* __restrict__ sT, const float* __restrict__ W,
    float* __restrict__ out) {
  const int b0 = blockIdx.x * 64;
  const int d0 = blockIdx.y * 64;
  const int t  = threadIdx.x;
  const int tx = t & 15;
  const int ty = t >> 4;

  __shared__ float As[16][64];
  __shared__ float Bs[16][64];
  float acc[4][4] = {};

  for (int k0 = 0; k0 < C_CH; k0 += 16) {
    const int kk  = t >> 6;
    const int col = t & 63;
#pragma unroll
    for (int r = 0; r < 4; ++r) {
      As[kk + r * 4][col] = sT[(size_t)(k0 + kk + r * 4) * B_NODES + b0 + col];
      Bs[kk + r * 4][col] = W[(size_t)(k0 + kk + r * 4) * C_CH + d0 + col];
    }
    __syncthreads();
#pragma unroll
    for (int k = 0; k < 16; ++k) {
      float a[4], bv[4];
#pragma unroll
      for (int i = 0; i < 4; ++i) a[i] = As[k][ty * 4 + i];
#pragma unroll
      for (int j = 0; j < 4; ++j) bv[j] = Bs[k][tx * 4 + j];
#pragma unroll
      for (int i = 0; i < 4; ++i)
#pragma unroll
        for (int j = 0; j < 4; ++j) acc[i][j] += a[i] * bv[j];
    }
    __syncthreads();
  }

#pragma unroll
  for (int i = 0; i < 4; ++i) {
    float4 v = make_float4(acc[i][0] * 0.0625f, acc[i][1] * 0.0625f,
                           acc[i][2] * 0.0625f, acc[i][3] * 0.0625f);
    *(float4*)(out + (size_t)(b0 + ty * 4 + i) * C_CH + d0 + tx * 4) = v;
  }
}

extern "C" void kernel_launch(void* const* d_in, const int* in_sizes, int n_in,
                              void* d_out, int out_size, void* d_ws, size_t ws_size,
                              hipStream_t stream) {
  const float* x  = (const float*)d_in[0];
  const float* U3 = (const float*)d_in[1];
  const float* U2 = (const float*)d_in[2];
  const float* U1 = (const float*)d_in[3];
  const float* w3 = (const float*)d_in[4];
  const float* w2 = (const float*)d_in[5];
  const float* w1 = (const float*)d_in[6];
  const float* Wl = (const float*)d_in[7];

  unsigned int* bfrag = (unsigned int*)((char*)d_ws + OFF_BF_BYTES);
  float*        sT    = (float*)((char*)d_ws + OFF_ST_BYTES);
  float*        out   = (float*)d_out;

  precompute_bfrag<<<dim3(KSTEPS, C_CH / 8), dim3(256), 0, stream>>>(
      U3, U2, U1, w3, w2, w1, bfrag);
  contract_mfma<<<dim3(C_CH / 4, B_NODES / (TILES_PER_WAVE * 16)), dim3(256), 0, stream>>>(
      x, (const short8*)bfrag, sT);
  linear_kernel<<<dim3(B_NODES / 64, C_CH / 64), dim3(256), 0, stream>>>(sT, Wl, out);
}